// Round 2
// baseline (1063.074 us; speedup 1.0000x reference)
//
#include <hip/hip_runtime.h>
#include <math.h>

#define BB 2
#define TT 2048
#define DD 2048
#define HH 16
#define KK 128

typedef _Float16 h4 __attribute__((ext_vector_type(4)));
typedef _Float16 v8h __attribute__((ext_vector_type(8)));
typedef float v4f __attribute__((ext_vector_type(4)));

// ---------------------------------------------------------------------------
// FALLBACK fp32 GEMM — used only if ws is too small for the f16 buffers.
// ---------------------------------------------------------------------------
__global__ __launch_bounds__(256) void gemm_nt3(const float* __restrict__ A,
                                                const float* __restrict__ W0,
                                                const float* __restrict__ W1,
                                                const float* __restrict__ W2,
                                                float* __restrict__ Cbase,
                                                int M, int N, int Kd) {
  __shared__ float As[8][128];
  __shared__ float Bs[8][128];
  const int z = blockIdx.z;
  const float* W = (z == 0) ? W0 : (z == 1) ? W1 : W2;
  float* C = Cbase + (size_t)z * M * N;
  const int tid = threadIdx.x;
  const int bm = blockIdx.y * 128;
  const int bn = blockIdx.x * 128;
  const int lrow = tid >> 1;
  const int lcol = (tid & 1) * 4;
  const int rm = (tid >> 4) * 8;
  const int rn = (tid & 15) * 8;
  const float* Ap = A + (size_t)(bm + lrow) * Kd + lcol;
  const float* Wp = W + (size_t)(bn + lrow) * Kd + lcol;
  float acc[8][8];
#pragma unroll
  for (int i = 0; i < 8; i++)
#pragma unroll
    for (int j = 0; j < 8; j++) acc[i][j] = 0.f;
  float4 av = *(const float4*)Ap;
  float4 wv = *(const float4*)Wp;
  for (int d0 = 0; d0 < Kd; d0 += 8) {
    __syncthreads();
    As[lcol + 0][lrow] = av.x; As[lcol + 1][lrow] = av.y;
    As[lcol + 2][lrow] = av.z; As[lcol + 3][lrow] = av.w;
    Bs[lcol + 0][lrow] = wv.x; Bs[lcol + 1][lrow] = wv.y;
    Bs[lcol + 2][lrow] = wv.z; Bs[lcol + 3][lrow] = wv.w;
    __syncthreads();
    if (d0 + 8 < Kd) {
      av = *(const float4*)(Ap + d0 + 8);
      wv = *(const float4*)(Wp + d0 + 8);
    }
#pragma unroll
    for (int kk = 0; kk < 8; kk++) {
      const float4 a0 = *(const float4*)&As[kk][rm];
      const float4 a1 = *(const float4*)&As[kk][rm + 4];
      const float4 b0 = *(const float4*)&Bs[kk][rn];
      const float4 b1 = *(const float4*)&Bs[kk][rn + 4];
      const float ar[8] = {a0.x, a0.y, a0.z, a0.w, a1.x, a1.y, a1.z, a1.w};
      const float br[8] = {b0.x, b0.y, b0.z, b0.w, b1.x, b1.y, b1.z, b1.w};
#pragma unroll
      for (int i = 0; i < 8; i++)
#pragma unroll
        for (int j = 0; j < 8; j++) acc[i][j] = fmaf(ar[i], br[j], acc[i][j]);
    }
  }
#pragma unroll
  for (int i = 0; i < 8; i++) {
    float* cp = C + (size_t)(bm + rm + i) * N + bn + rn;
    float4 c0 = {acc[i][0], acc[i][1], acc[i][2], acc[i][3]};
    float4 c1 = {acc[i][4], acc[i][5], acc[i][6], acc[i][7]};
    *(float4*)cp = c0;
    *(float4*)(cp + 4) = c1;
  }
}

// ---------------------------------------------------------------------------
// Convert: x -> xh + xl (f16 hi/lo split), Wq/Wk/Wv -> Wf (single f16).
// ---------------------------------------------------------------------------
__global__ __launch_bounds__(256) void convert_f16(
    const float* __restrict__ x, const float* __restrict__ Wq,
    const float* __restrict__ Wk, const float* __restrict__ Wv,
    _Float16* __restrict__ xh, _Float16* __restrict__ xl,
    _Float16* __restrict__ Wf) {
  const size_t N4X = (size_t)BB * TT * DD / 4;
  const size_t N4W = (size_t)(HH * KK) * DD / 4;
  const size_t i = (size_t)blockIdx.x * 256 + threadIdx.x;
  if (i < N4X) {
    const float4 v = ((const float4*)x)[i];
    h4 hi, lo;
    hi.x = (_Float16)v.x; hi.y = (_Float16)v.y;
    hi.z = (_Float16)v.z; hi.w = (_Float16)v.w;
    lo.x = (_Float16)(v.x - (float)hi.x);
    lo.y = (_Float16)(v.y - (float)hi.y);
    lo.z = (_Float16)(v.z - (float)hi.z);
    lo.w = (_Float16)(v.w - (float)hi.w);
    ((h4*)xh)[i] = hi;
    ((h4*)xl)[i] = lo;
  } else {
    const size_t j = i - N4X;
    const float* Ws = (j < N4W) ? Wq : (j < 2 * N4W) ? Wk : Wv;
    const size_t jj = (j < N4W) ? j : (j < 2 * N4W) ? (j - N4W) : (j - 2 * N4W);
    const float4 v = ((const float4*)Ws)[jj];
    h4 hi;
    hi.x = (_Float16)v.x; hi.y = (_Float16)v.y;
    hi.z = (_Float16)v.z; hi.w = (_Float16)v.w;
    ((h4*)Wf)[j] = hi;
  }
}

// ---------------------------------------------------------------------------
// MFMA GEMM: C[z] = xh*W[z]^T + xl*W[z]^T  (f16 in, fp32 out) — m97 structure
// ---------------------------------------------------------------------------
#define GLDS(gp, lp)                                              \
  __builtin_amdgcn_global_load_lds(                               \
      (const __attribute__((address_space(1))) void*)(gp),        \
      (__attribute__((address_space(3))) void*)(lp), 16, 0, 0)

__global__ __launch_bounds__(256) void gemm_mfma(
    const _Float16* __restrict__ xh, const _Float16* __restrict__ xl,
    const _Float16* __restrict__ Wf, float* __restrict__ Cbase) {
  __shared__ float4 lraw[1536];  // 24 KB = Ah | Al | Bs
  _Float16* Ah = (_Float16*)lraw;
  _Float16* Al = Ah + 4096;
  _Float16* Bs = Al + 4096;

  const int z = blockIdx.z;
  const _Float16* W = Wf + (size_t)z * DD * (HH * KK);
  float* C = Cbase + (size_t)z * (BB * TT) * (HH * KK);

  const int tid = threadIdx.x;
  const int w = tid >> 6;
  const int lane = tid & 63;
  const int bm = blockIdx.y * 128;
  const int bn = blockIdx.x * 128;
  const int wm = (w & 1) * 64;
  const int wn = (w >> 1) * 64;
  const int m16 = lane & 15;
  const int quad = lane >> 4;

  const _Float16* gAh = xh + (size_t)(bm + (tid >> 2)) * DD + (tid & 3) * 8;
  const _Float16* gAl = xl + (size_t)(bm + (tid >> 2)) * DD + (tid & 3) * 8;
  const _Float16* gB = W + (size_t)(bn + (tid >> 2)) * DD + (tid & 3) * 8;
  const int lb = w * 512;

  v4f acc[4][4];
#pragma unroll
  for (int i = 0; i < 4; i++)
#pragma unroll
    for (int j = 0; j < 4; j++) acc[i][j] = (v4f){0.f, 0.f, 0.f, 0.f};

  for (int d0 = 0; d0 < DD; d0 += 32) {
    GLDS(gAh + d0, Ah + lb);
    GLDS(gAh + d0 + 64 * DD, Ah + 2048 + lb);
    GLDS(gAl + d0, Al + lb);
    GLDS(gAl + d0 + 64 * DD, Al + 2048 + lb);
    GLDS(gB + d0, Bs + lb);
    GLDS(gB + d0 + 64 * DD, Bs + 2048 + lb);
    __syncthreads();
    v8h ah[4], al[4], bw[4];
#pragma unroll
    for (int i = 0; i < 4; i++) {
      ah[i] = *(const v8h*)&Ah[(wm + i * 16 + m16) * 32 + quad * 8];
      al[i] = *(const v8h*)&Al[(wm + i * 16 + m16) * 32 + quad * 8];
      bw[i] = *(const v8h*)&Bs[(wn + i * 16 + m16) * 32 + quad * 8];
    }
#pragma unroll
    for (int mi = 0; mi < 4; mi++)
#pragma unroll
      for (int ni = 0; ni < 4; ni++) {
        acc[mi][ni] = __builtin_amdgcn_mfma_f32_16x16x32_f16(ah[mi], bw[ni],
                                                             acc[mi][ni], 0, 0, 0);
        acc[mi][ni] = __builtin_amdgcn_mfma_f32_16x16x32_f16(al[mi], bw[ni],
                                                             acc[mi][ni], 0, 0, 0);
      }
    __syncthreads();
  }
#pragma unroll
  for (int mi = 0; mi < 4; mi++) {
#pragma unroll
    for (int r = 0; r < 4; r++) {
      float* cp =
          C + (size_t)(bm + wm + mi * 16 + quad * 4 + r) * (HH * KK) + bn + wn + m16;
#pragma unroll
      for (int ni = 0; ni < 4; ni++) cp[ni * 16] = acc[mi][ni][r];
    }
  }
}

// ---------------------------------------------------------------------------
// alpha/beta projections (unchanged)
// ---------------------------------------------------------------------------
__global__ __launch_bounds__(64) void ab_proj(const float* __restrict__ x,
                                              const float* __restrict__ Wa,
                                              const float* __restrict__ ba,
                                              const float* __restrict__ Wb,
                                              const float* __restrict__ bb,
                                              float* __restrict__ abq) {
  const int row = blockIdx.x;
  const int g = blockIdx.y;
  const int h0 = (g & 1) * 8;
  const bool isA = (g < 2);
  const float* W = isA ? Wa : Wb;
  const int lane = threadIdx.x;
  const float* xr = x + (size_t)row * DD;
  float acc[8];
#pragma unroll
  for (int j = 0; j < 8; j++) acc[j] = 0.f;
  for (int d = lane; d < DD; d += 64) {
    const float xv = xr[d];
#pragma unroll
    for (int j = 0; j < 8; j++)
      acc[j] = fmaf(xv, W[(size_t)(h0 + j) * DD + d], acc[j]);
  }
#pragma unroll
  for (int j = 0; j < 8; j++) {
#pragma unroll
    for (int off = 32; off > 0; off >>= 1) acc[j] += __shfl_xor(acc[j], off, 64);
  }
  if (lane == 0) {
    if (isA) {
#pragma unroll
      for (int j = 0; j < 8; j++) {
        const float z = acc[j] + ba[h0 + j];
        abq[((size_t)row * HH + h0 + j) * 4 + 0] = 1.0f / (1.0f + expf(-z));
      }
    } else {
#pragma unroll
      for (int j = 0; j < 8; j++) {
        const float z = acc[j] + bb[h0 + j];
        const float sp = (z > 20.f) ? z : log1pf(expf(z));
        abq[((size_t)row * HH + h0 + j) * 4 + 1] = sp * 0.08838834764831845f;
      }
    }
  }
}

// ---------------------------------------------------------------------------
// l2-normalize q,k in place; kq = dot(qn,kn) -> abq slot 2 (unchanged)
// ---------------------------------------------------------------------------
__global__ __launch_bounds__(256) void norm_qk(float* __restrict__ q,
                                               float* __restrict__ k,
                                               float* __restrict__ abq) {
  const int vec = blockIdx.x * 4 + (threadIdx.x >> 6);
  const int l = threadIdx.x & 63;
  float* qp = q + (size_t)vec * 128;
  float* kp = k + (size_t)vec * 128;
  float q0 = qp[l], q1 = qp[l + 64];
  float k0 = kp[l], k1 = kp[l + 64];
  float sq = q0 * q0 + q1 * q1;
  float sk = k0 * k0 + k1 * k1;
#pragma unroll
  for (int off = 32; off > 0; off >>= 1) {
    sq += __shfl_xor(sq, off, 64);
    sk += __shfl_xor(sk, off, 64);
  }
  const float iq = 1.0f / fmaxf(sqrtf(sq), 1e-12f);
  const float ik = 1.0f / fmaxf(sqrtf(sk), 1e-12f);
  q0 *= iq; q1 *= iq; k0 *= ik; k1 *= ik;
  qp[l] = q0; qp[l + 64] = q1;
  kp[l] = k0; kp[l + 64] = k1;
  float pq = q0 * k0 + q1 * k1;
#pragma unroll
  for (int off = 32; off > 0; off >>= 1) pq += __shfl_xor(pq, off, 64);
  if (l == 0) abq[(size_t)vec * 4 + 2] = pq;
}

// ---------------------------------------------------------------------------
// Scan v6: 32-lane row-groups (4 state floats/thread) -> 131072 threads =
// 512 blocks = 2 blocks/CU = 2 waves/SIMD for latency hiding (v4 had 1).
// Row's 32 K-slots map to lanes {0-15}U{32-47} (resp {16-31}U{48-63}):
// allreduce = 4 DPP stages within 16 lanes + one __shfl_xor(32) stage
// (compiler-generated cross-32 exchange; v5's inline-asm permlane was the
// correctness suspect and is removed).
// Keeps the no-copy depth-8 prefetch + sched_barrier(0) pinning from v4.
// ---------------------------------------------------------------------------
#define DPP_ADD(x, ctrl)                                                     \
  ((x) + __int_as_float(__builtin_amdgcn_update_dpp(                         \
             0, __float_as_int(x), (ctrl), 0xF, 0xF, true)))

#define SCAN_STEP(kc, qc, vc, ac, store_ptr)                                   \
  {                                                                            \
    float dk = fmaf(S0, kc.x, fmaf(S1, kc.y, fmaf(S2, kc.z, S3 * kc.w)));      \
    float dq = fmaf(S0, qc.x, fmaf(S1, qc.y, fmaf(S2, qc.z, S3 * qc.w)));      \
    dk = DPP_ADD(dk, 0xB1);  dq = DPP_ADD(dq, 0xB1);   /* width 2  */          \
    dk = DPP_ADD(dk, 0x4E);  dq = DPP_ADD(dq, 0x4E);   /* width 4  */          \
    dk = DPP_ADD(dk, 0x141); dq = DPP_ADD(dq, 0x141);  /* width 8  */          \
    dk = DPP_ADD(dk, 0x140); dq = DPP_ADD(dq, 0x140);  /* width 16 */          \
    dk += __shfl_xor(dk, 32, 64);                      /* width 32 */          \
    dq += __shfl_xor(dq, 32, 64);                                              \
    const float u = ac.y * fmaf(-ac.x, dk, vc);                                \
    const float oo = fmaf(ac.x, dq, u * ac.z);                                 \
    S0 = fmaf(ac.x, S0, u * kc.x);                                             \
    S1 = fmaf(ac.x, S1, u * kc.y);                                             \
    S2 = fmaf(ac.x, S2, u * kc.z);                                             \
    S3 = fmaf(ac.x, S3, u * kc.w);                                             \
    if (ks == 0) *(store_ptr) = oo;                                            \
  }

#define PD 8  // prefetch depth

__global__ __launch_bounds__(256, 2) void scan_kernel(
    const float* __restrict__ q, const float* __restrict__ k,
    const float* __restrict__ v, const float* __restrict__ abq,
    float* __restrict__ o) {
  const int bid = blockIdx.x;  // = s*32 + bh
  const int bh = bid & 31;
  const int s = bid >> 5;  // 0..15
  const int h = bh & 15;
  const int b = bh >> 4;
  const int tid = threadIdx.x;
  const int w = tid >> 6;
  const int lane = tid & 63;
  const int rg = (lane >> 4) & 1;                   // row within wave (0..1)
  const int ks = (lane & 15) | ((lane >> 5) << 4);  // k-slot 0..31 (4 floats)
  const int vrow = s * 8 + w * 2 + rg;

  const size_t base = (size_t)b * TT * 2048 + (size_t)h * KK;
  const float* kb = k + base + ks * 4;
  const float* qb = q + base + ks * 4;
  const float* vb = v + base + vrow;
  const float* ab = abq + ((size_t)b * TT * HH + h) * 4;
  float* ob = o + base + vrow;

  float S0 = 0.f, S1 = 0.f, S2 = 0.f, S3 = 0.f;

  float4 kf[PD], qf[PD], af[PD];
  float vf[PD];
#pragma unroll
  for (int d = 0; d < PD; d++) {
    kf[d] = *(const float4*)(kb + d * 2048);
    qf[d] = *(const float4*)(qb + d * 2048);
    vf[d] = vb[d * 2048];
    af[d] = *(const float4*)(ab + d * 64);
  }

  int off = 0;   // uniform element offset, +2048 per step
  int aoff = 0;  // uniform abq offset, +64 per step
  for (int t0 = 0; t0 < TT - PD; t0 += PD) {
#pragma unroll
    for (int j = 0; j < PD; j++) {
      // consume slot j (no copy — loads below overwrite it afterwards)
      SCAN_STEP(kf[j], qf[j], vf[j], af[j], ob + off + j * 2048);
      // reload slot j with step t0+j+PD
      kf[j] = *(const float4*)(kb + off + (j + PD) * 2048);
      qf[j] = *(const float4*)(qb + off + (j + PD) * 2048);
      vf[j] = vb[off + (j + PD) * 2048];
      af[j] = *(const float4*)(ab + aoff + (j + PD) * 64);
      __builtin_amdgcn_sched_barrier(0);  // loads may not sink past here
    }
    off += PD * 2048;
    aoff += PD * 64;
  }
  // final PD steps: consume only
#pragma unroll
  for (int j = 0; j < PD; j++) {
    SCAN_STEP(kf[j], qf[j], vf[j], af[j], ob + off + j * 2048);
  }
}

// ---------------------------------------------------------------------------
extern "C" void kernel_launch(void* const* d_in, const int* in_sizes, int n_in,
                              void* d_out, int out_size, void* d_ws,
                              size_t ws_size, hipStream_t stream) {
  const float* x = (const float*)d_in[0];
  const float* Wq = (const float*)d_in[1];
  const float* Wk = (const float*)d_in[2];
  const float* Wv = (const float*)d_in[3];
  const float* Wa = (const float*)d_in[4];
  const float* ba = (const float*)d_in[5];
  const float* Wb = (const float*)d_in[6];
  const float* bb = (const float*)d_in[7];
  float* out = (float*)d_out;
  float* ws = (float*)d_ws;

  const size_t PROJ = (size_t)BB * TT * HH * KK;  // 8,388,608
  const size_t NABQ = (size_t)BB * TT * HH * 4;
  float* qw = ws;
  float* kw = ws + PROJ;
  float* vw = ws + 2 * PROJ;
  float* abq = ws + 3 * PROJ;
  _Float16* xh = (_Float16*)(abq + NABQ);
  _Float16* xl = xh + (size_t)BB * TT * DD;
  _Float16* Wf = xl + (size_t)BB * TT * DD;
  const size_t NEED = (3 * PROJ + NABQ) * 4 +
                      ((size_t)BB * TT * DD * 2 + 3 * (size_t)(HH * KK) * DD) * 2;

  const int M = BB * TT;  // 4096
  const int N = HH * KK;  // 2048
  if (ws_size >= NEED) {
    const int cgrid = (int)(((size_t)BB * TT * DD / 4 + 3 * (size_t)N * DD / 4) / 256);
    convert_f16<<<cgrid, 256, 0, stream>>>(x, Wq, Wk, Wv, xh, xl, Wf);
    gemm_mfma<<<dim3(N / 128, M / 128, 3), 256, 0, stream>>>(xh, xl, Wf, qw);
  } else {
    gemm_nt3<<<dim3(N / 128, M / 128, 3), 256, 0, stream>>>(x, Wq, Wk, Wv, qw,
                                                            M, N, DD);
  }
  ab_proj<<<dim3(M, 4), 64, 0, stream>>>(x, Wa, ba, Wb, bb, abq);
  norm_qk<<<(BB * TT * HH) / 4, 256, 0, stream>>>(qw, kw, abq);
  scan_kernel<<<BB * HH * 16, 256, 0, stream>>>(qw, kw, vw, abq, out);
}

// Round 3
// 774.637 us; speedup vs baseline: 1.3724x; 1.3724x over previous
//
#include <hip/hip_runtime.h>
#include <math.h>

#define BB 2
#define TT 2048
#define DD 2048
#define HH 16
#define KK 128

typedef _Float16 h4 __attribute__((ext_vector_type(4)));
typedef _Float16 v8h __attribute__((ext_vector_type(8)));
typedef float v4f __attribute__((ext_vector_type(4)));
typedef unsigned int u2v __attribute__((ext_vector_type(2)));

// ---------------------------------------------------------------------------
// FALLBACK fp32 GEMM — used only if ws is too small for the f16 buffers.
// ---------------------------------------------------------------------------
__global__ __launch_bounds__(256) void gemm_nt3(const float* __restrict__ A,
                                                const float* __restrict__ W0,
                                                const float* __restrict__ W1,
                                                const float* __restrict__ W2,
                                                float* __restrict__ Cbase,
                                                int M, int N, int Kd) {
  __shared__ float As[8][128];
  __shared__ float Bs[8][128];
  const int z = blockIdx.z;
  const float* W = (z == 0) ? W0 : (z == 1) ? W1 : W2;
  float* C = Cbase + (size_t)z * M * N;
  const int tid = threadIdx.x;
  const int bm = blockIdx.y * 128;
  const int bn = blockIdx.x * 128;
  const int lrow = tid >> 1;
  const int lcol = (tid & 1) * 4;
  const int rm = (tid >> 4) * 8;
  const int rn = (tid & 15) * 8;
  const float* Ap = A + (size_t)(bm + lrow) * Kd + lcol;
  const float* Wp = W + (size_t)(bn + lrow) * Kd + lcol;
  float acc[8][8];
#pragma unroll
  for (int i = 0; i < 8; i++)
#pragma unroll
    for (int j = 0; j < 8; j++) acc[i][j] = 0.f;
  float4 av = *(const float4*)Ap;
  float4 wv = *(const float4*)Wp;
  for (int d0 = 0; d0 < Kd; d0 += 8) {
    __syncthreads();
    As[lcol + 0][lrow] = av.x; As[lcol + 1][lrow] = av.y;
    As[lcol + 2][lrow] = av.z; As[lcol + 3][lrow] = av.w;
    Bs[lcol + 0][lrow] = wv.x; Bs[lcol + 1][lrow] = wv.y;
    Bs[lcol + 2][lrow] = wv.z; Bs[lcol + 3][lrow] = wv.w;
    __syncthreads();
    if (d0 + 8 < Kd) {
      av = *(const float4*)(Ap + d0 + 8);
      wv = *(const float4*)(Wp + d0 + 8);
    }
#pragma unroll
    for (int kk = 0; kk < 8; kk++) {
      const float4 a0 = *(const float4*)&As[kk][rm];
      const float4 a1 = *(const float4*)&As[kk][rm + 4];
      const float4 b0 = *(const float4*)&Bs[kk][rn];
      const float4 b1 = *(const float4*)&Bs[kk][rn + 4];
      const float ar[8] = {a0.x, a0.y, a0.z, a0.w, a1.x, a1.y, a1.z, a1.w};
      const float br[8] = {b0.x, b0.y, b0.z, b0.w, b1.x, b1.y, b1.z, b1.w};
#pragma unroll
      for (int i = 0; i < 8; i++)
#pragma unroll
        for (int j = 0; j < 8; j++) acc[i][j] = fmaf(ar[i], br[j], acc[i][j]);
    }
  }
#pragma unroll
  for (int i = 0; i < 8; i++) {
    float* cp = C + (size_t)(bm + rm + i) * N + bn + rn;
    float4 c0 = {acc[i][0], acc[i][1], acc[i][2], acc[i][3]};
    float4 c1 = {acc[i][4], acc[i][5], acc[i][6], acc[i][7]};
    *(float4*)cp = c0;
    *(float4*)(cp + 4) = c1;
  }
}

// ---------------------------------------------------------------------------
// Convert: x -> xh + xl (f16 hi/lo split), Wq/Wk/Wv -> Wf (single f16).
// ---------------------------------------------------------------------------
__global__ __launch_bounds__(256) void convert_f16(
    const float* __restrict__ x, const float* __restrict__ Wq,
    const float* __restrict__ Wk, const float* __restrict__ Wv,
    _Float16* __restrict__ xh, _Float16* __restrict__ xl,
    _Float16* __restrict__ Wf) {
  const size_t N4X = (size_t)BB * TT * DD / 4;
  const size_t N4W = (size_t)(HH * KK) * DD / 4;
  const size_t i = (size_t)blockIdx.x * 256 + threadIdx.x;
  if (i < N4X) {
    const float4 v = ((const float4*)x)[i];
    h4 hi, lo;
    hi.x = (_Float16)v.x; hi.y = (_Float16)v.y;
    hi.z = (_Float16)v.z; hi.w = (_Float16)v.w;
    lo.x = (_Float16)(v.x - (float)hi.x);
    lo.y = (_Float16)(v.y - (float)hi.y);
    lo.z = (_Float16)(v.z - (float)hi.z);
    lo.w = (_Float16)(v.w - (float)hi.w);
    ((h4*)xh)[i] = hi;
    ((h4*)xl)[i] = lo;
  } else {
    const size_t j = i - N4X;
    const float* Ws = (j < N4W) ? Wq : (j < 2 * N4W) ? Wk : Wv;
    const size_t jj = (j < N4W) ? j : (j < 2 * N4W) ? (j - N4W) : (j - 2 * N4W);
    const float4 v = ((const float4*)Ws)[jj];
    h4 hi;
    hi.x = (_Float16)v.x; hi.y = (_Float16)v.y;
    hi.z = (_Float16)v.z; hi.w = (_Float16)v.w;
    ((h4*)Wf)[j] = hi;
  }
}

// ---------------------------------------------------------------------------
// MFMA GEMM: C[z] = xh*W[z]^T + xl*W[z]^T  (f16 in, fp32 out) — m97 structure
// ---------------------------------------------------------------------------
#define GLDS(gp, lp)                                              \
  __builtin_amdgcn_global_load_lds(                               \
      (const __attribute__((address_space(1))) void*)(gp),        \
      (__attribute__((address_space(3))) void*)(lp), 16, 0, 0)

__global__ __launch_bounds__(256) void gemm_mfma(
    const _Float16* __restrict__ xh, const _Float16* __restrict__ xl,
    const _Float16* __restrict__ Wf, float* __restrict__ Cbase) {
  __shared__ float4 lraw[1536];  // 24 KB = Ah | Al | Bs
  _Float16* Ah = (_Float16*)lraw;
  _Float16* Al = Ah + 4096;
  _Float16* Bs = Al + 4096;

  const int z = blockIdx.z;
  const _Float16* W = Wf + (size_t)z * DD * (HH * KK);
  float* C = Cbase + (size_t)z * (BB * TT) * (HH * KK);

  const int tid = threadIdx.x;
  const int w = tid >> 6;
  const int lane = tid & 63;
  const int bm = blockIdx.y * 128;
  const int bn = blockIdx.x * 128;
  const int wm = (w & 1) * 64;
  const int wn = (w >> 1) * 64;
  const int m16 = lane & 15;
  const int quad = lane >> 4;

  const _Float16* gAh = xh + (size_t)(bm + (tid >> 2)) * DD + (tid & 3) * 8;
  const _Float16* gAl = xl + (size_t)(bm + (tid >> 2)) * DD + (tid & 3) * 8;
  const _Float16* gB = W + (size_t)(bn + (tid >> 2)) * DD + (tid & 3) * 8;
  const int lb = w * 512;

  v4f acc[4][4];
#pragma unroll
  for (int i = 0; i < 4; i++)
#pragma unroll
    for (int j = 0; j < 4; j++) acc[i][j] = (v4f){0.f, 0.f, 0.f, 0.f};

  for (int d0 = 0; d0 < DD; d0 += 32) {
    GLDS(gAh + d0, Ah + lb);
    GLDS(gAh + d0 + 64 * DD, Ah + 2048 + lb);
    GLDS(gAl + d0, Al + lb);
    GLDS(gAl + d0 + 64 * DD, Al + 2048 + lb);
    GLDS(gB + d0, Bs + lb);
    GLDS(gB + d0 + 64 * DD, Bs + 2048 + lb);
    __syncthreads();
    v8h ah[4], al[4], bw[4];
#pragma unroll
    for (int i = 0; i < 4; i++) {
      ah[i] = *(const v8h*)&Ah[(wm + i * 16 + m16) * 32 + quad * 8];
      al[i] = *(const v8h*)&Al[(wm + i * 16 + m16) * 32 + quad * 8];
      bw[i] = *(const v8h*)&Bs[(wn + i * 16 + m16) * 32 + quad * 8];
    }
#pragma unroll
    for (int mi = 0; mi < 4; mi++)
#pragma unroll
      for (int ni = 0; ni < 4; ni++) {
        acc[mi][ni] = __builtin_amdgcn_mfma_f32_16x16x32_f16(ah[mi], bw[ni],
                                                             acc[mi][ni], 0, 0, 0);
        acc[mi][ni] = __builtin_amdgcn_mfma_f32_16x16x32_f16(al[mi], bw[ni],
                                                             acc[mi][ni], 0, 0, 0);
      }
    __syncthreads();
  }
#pragma unroll
  for (int mi = 0; mi < 4; mi++) {
#pragma unroll
    for (int r = 0; r < 4; r++) {
      float* cp =
          C + (size_t)(bm + wm + mi * 16 + quad * 4 + r) * (HH * KK) + bn + wn + m16;
#pragma unroll
      for (int ni = 0; ni < 4; ni++) cp[ni * 16] = acc[mi][ni][r];
    }
  }
}

// ---------------------------------------------------------------------------
// alpha/beta projections (unchanged)
// ---------------------------------------------------------------------------
__global__ __launch_bounds__(64) void ab_proj(const float* __restrict__ x,
                                              const float* __restrict__ Wa,
                                              const float* __restrict__ ba,
                                              const float* __restrict__ Wb,
                                              const float* __restrict__ bb,
                                              float* __restrict__ abq) {
  const int row = blockIdx.x;
  const int g = blockIdx.y;
  const int h0 = (g & 1) * 8;
  const bool isA = (g < 2);
  const float* W = isA ? Wa : Wb;
  const int lane = threadIdx.x;
  const float* xr = x + (size_t)row * DD;
  float acc[8];
#pragma unroll
  for (int j = 0; j < 8; j++) acc[j] = 0.f;
  for (int d = lane; d < DD; d += 64) {
    const float xv = xr[d];
#pragma unroll
    for (int j = 0; j < 8; j++)
      acc[j] = fmaf(xv, W[(size_t)(h0 + j) * DD + d], acc[j]);
  }
#pragma unroll
  for (int j = 0; j < 8; j++) {
#pragma unroll
    for (int off = 32; off > 0; off >>= 1) acc[j] += __shfl_xor(acc[j], off, 64);
  }
  if (lane == 0) {
    if (isA) {
#pragma unroll
      for (int j = 0; j < 8; j++) {
        const float z = acc[j] + ba[h0 + j];
        abq[((size_t)row * HH + h0 + j) * 4 + 0] = 1.0f / (1.0f + expf(-z));
      }
    } else {
#pragma unroll
      for (int j = 0; j < 8; j++) {
        const float z = acc[j] + bb[h0 + j];
        const float sp = (z > 20.f) ? z : log1pf(expf(z));
        abq[((size_t)row * HH + h0 + j) * 4 + 1] = sp * 0.08838834764831845f;
      }
    }
  }
}

// ---------------------------------------------------------------------------
// l2-normalize q,k in place; kq = dot(qn,kn) -> abq slot 2 (unchanged)
// ---------------------------------------------------------------------------
__global__ __launch_bounds__(256) void norm_qk(float* __restrict__ q,
                                               float* __restrict__ k,
                                               float* __restrict__ abq) {
  const int vec = blockIdx.x * 4 + (threadIdx.x >> 6);
  const int l = threadIdx.x & 63;
  float* qp = q + (size_t)vec * 128;
  float* kp = k + (size_t)vec * 128;
  float q0 = qp[l], q1 = qp[l + 64];
  float k0 = kp[l], k1 = kp[l + 64];
  float sq = q0 * q0 + q1 * q1;
  float sk = k0 * k0 + k1 * k1;
#pragma unroll
  for (int off = 32; off > 0; off >>= 1) {
    sq += __shfl_xor(sq, off, 64);
    sk += __shfl_xor(sk, off, 64);
  }
  const float iq = 1.0f / fmaxf(sqrtf(sq), 1e-12f);
  const float ik = 1.0f / fmaxf(sqrtf(sk), 1e-12f);
  q0 *= iq; q1 *= iq; k0 *= ik; k1 *= ik;
  qp[l] = q0; qp[l + 64] = q1;
  kp[l] = k0; kp[l + 64] = k1;
  float pq = q0 * k0 + q1 * k1;
#pragma unroll
  for (int off = 32; off > 0; off >>= 1) pq += __shfl_xor(pq, off, 64);
  if (l == 0) abq[(size_t)vec * 4 + 2] = pq;
}

// ---------------------------------------------------------------------------
// Scan v7: 32-lane row-groups, 4 state floats/thread, 2 waves/SIMD.
// Cross-32 allreduce stage now uses the __builtin_amdgcn_permlane32_swap
// BUILTIN (single VALU instr, both results as distinct SSA values — no
// register-coalescing hazard like v5's inline asm, no LDS pipe / lgkmcnt
// like v6's __shfl_xor which cost +260 µs). Reduce = 4 DPP stages within
// 16 lanes + 1 permlane32_swap: entirely VALU, chain ~60-80 cyc.
// Keeps the no-copy depth-8 prefetch + sched_barrier(0) pinning.
// ---------------------------------------------------------------------------
#define DPP_ADD(x, ctrl)                                                     \
  ((x) + __int_as_float(__builtin_amdgcn_update_dpp(                         \
             0, __float_as_int(x), (ctrl), 0xF, 0xF, true)))

__device__ __forceinline__ float xadd32(float x) {
  // returns x[lane] + x[lane^32] in every lane (pure VALU)
  const u2v r = __builtin_amdgcn_permlane32_swap(__float_as_uint(x),
                                                 __float_as_uint(x), false,
                                                 false);
  return __uint_as_float(r.x) + __uint_as_float(r.y);
}

#define SCAN_STEP(kc, qc, vc, ac, store_ptr)                                   \
  {                                                                            \
    float dk = fmaf(S0, kc.x, fmaf(S1, kc.y, fmaf(S2, kc.z, S3 * kc.w)));      \
    float dq = fmaf(S0, qc.x, fmaf(S1, qc.y, fmaf(S2, qc.z, S3 * qc.w)));      \
    dk = DPP_ADD(dk, 0xB1);  dq = DPP_ADD(dq, 0xB1);   /* width 2  */          \
    dk = DPP_ADD(dk, 0x4E);  dq = DPP_ADD(dq, 0x4E);   /* width 4  */          \
    dk = DPP_ADD(dk, 0x141); dq = DPP_ADD(dq, 0x141);  /* width 8  */          \
    dk = DPP_ADD(dk, 0x140); dq = DPP_ADD(dq, 0x140);  /* width 16 */          \
    dk = xadd32(dk);         dq = xadd32(dq);          /* width 32 */          \
    const float u = ac.y * fmaf(-ac.x, dk, vc);                                \
    const float oo = fmaf(ac.x, dq, u * ac.z);                                 \
    S0 = fmaf(ac.x, S0, u * kc.x);                                             \
    S1 = fmaf(ac.x, S1, u * kc.y);                                             \
    S2 = fmaf(ac.x, S2, u * kc.z);                                             \
    S3 = fmaf(ac.x, S3, u * kc.w);                                             \
    if (ks == 0) *(store_ptr) = oo;                                            \
  }

#define PD 8  // prefetch depth

__global__ __launch_bounds__(256, 2) void scan_kernel(
    const float* __restrict__ q, const float* __restrict__ k,
    const float* __restrict__ v, const float* __restrict__ abq,
    float* __restrict__ o) {
  const int bid = blockIdx.x;  // = s*32 + bh
  const int bh = bid & 31;
  const int s = bid >> 5;  // 0..15
  const int h = bh & 15;
  const int b = bh >> 4;
  const int tid = threadIdx.x;
  const int w = tid >> 6;
  const int lane = tid & 63;
  const int rg = (lane >> 4) & 1;                   // row within wave (0..1)
  const int ks = (lane & 15) | ((lane >> 5) << 4);  // k-slot 0..31 (4 floats)
  const int vrow = s * 8 + w * 2 + rg;

  const size_t base = (size_t)b * TT * 2048 + (size_t)h * KK;
  const float* kb = k + base + ks * 4;
  const float* qb = q + base + ks * 4;
  const float* vb = v + base + vrow;
  const float* ab = abq + ((size_t)b * TT * HH + h) * 4;
  float* ob = o + base + vrow;

  float S0 = 0.f, S1 = 0.f, S2 = 0.f, S3 = 0.f;

  float4 kf[PD], qf[PD], af[PD];
  float vf[PD];
#pragma unroll
  for (int d = 0; d < PD; d++) {
    kf[d] = *(const float4*)(kb + d * 2048);
    qf[d] = *(const float4*)(qb + d * 2048);
    vf[d] = vb[d * 2048];
    af[d] = *(const float4*)(ab + d * 64);
  }

  int off = 0;   // uniform element offset, +2048 per step
  int aoff = 0;  // uniform abq offset, +64 per step
  for (int t0 = 0; t0 < TT - PD; t0 += PD) {
#pragma unroll
    for (int j = 0; j < PD; j++) {
      // consume slot j (no copy — loads below overwrite it afterwards)
      SCAN_STEP(kf[j], qf[j], vf[j], af[j], ob + off + j * 2048);
      // reload slot j with step t0+j+PD
      kf[j] = *(const float4*)(kb + off + (j + PD) * 2048);
      qf[j] = *(const float4*)(qb + off + (j + PD) * 2048);
      vf[j] = vb[off + (j + PD) * 2048];
      af[j] = *(const float4*)(ab + aoff + (j + PD) * 64);
      __builtin_amdgcn_sched_barrier(0);  // loads may not sink past here
    }
    off += PD * 2048;
    aoff += PD * 64;
  }
  // final PD steps: consume only
#pragma unroll
  for (int j = 0; j < PD; j++) {
    SCAN_STEP(kf[j], qf[j], vf[j], af[j], ob + off + j * 2048);
  }
}

// ---------------------------------------------------------------------------
extern "C" void kernel_launch(void* const* d_in, const int* in_sizes, int n_in,
                              void* d_out, int out_size, void* d_ws,
                              size_t ws_size, hipStream_t stream) {
  const float* x = (const float*)d_in[0];
  const float* Wq = (const float*)d_in[1];
  const float* Wk = (const float*)d_in[2];
  const float* Wv = (const float*)d_in[3];
  const float* Wa = (const float*)d_in[4];
  const float* ba = (const float*)d_in[5];
  const float* Wb = (const float*)d_in[6];
  const float* bb = (const float*)d_in[7];
  float* out = (float*)d_out;
  float* ws = (float*)d_ws;

  const size_t PROJ = (size_t)BB * TT * HH * KK;  // 8,388,608
  const size_t NABQ = (size_t)BB * TT * HH * 4;
  float* qw = ws;
  float* kw = ws + PROJ;
  float* vw = ws + 2 * PROJ;
  float* abq = ws + 3 * PROJ;
  _Float16* xh = (_Float16*)(abq + NABQ);
  _Float16* xl = xh + (size_t)BB * TT * DD;
  _Float16* Wf = xl + (size_t)BB * TT * DD;
  const size_t NEED = (3 * PROJ + NABQ) * 4 +
                      ((size_t)BB * TT * DD * 2 + 3 * (size_t)(HH * KK) * DD) * 2;

  const int M = BB * TT;  // 4096
  const int N = HH * KK;  // 2048
  if (ws_size >= NEED) {
    const int cgrid = (int)(((size_t)BB * TT * DD / 4 + 3 * (size_t)N * DD / 4) / 256);
    convert_f16<<<cgrid, 256, 0, stream>>>(x, Wq, Wk, Wv, xh, xl, Wf);
    gemm_mfma<<<dim3(N / 128, M / 128, 3), 256, 0, stream>>>(xh, xl, Wf, qw);
  } else {
    gemm_nt3<<<dim3(N / 128, M / 128, 3), 256, 0, stream>>>(x, Wq, Wk, Wv, qw,
                                                            M, N, DD);
  }
  ab_proj<<<dim3(M, 4), 64, 0, stream>>>(x, Wa, ba, Wb, bb, abq);
  norm_qk<<<(BB * TT * HH) / 4, 256, 0, stream>>>(qw, kw, abq);
  scan_kernel<<<BB * HH * 16, 256, 0, stream>>>(qw, kw, vw, abq, out);
}

// Round 5
// 726.014 us; speedup vs baseline: 1.4643x; 1.0670x over previous
//
#include <hip/hip_runtime.h>
#include <math.h>

#define BB 2
#define TT 2048
#define DD 2048
#define HH 16
#define KK 128

typedef _Float16 h4 __attribute__((ext_vector_type(4)));
typedef _Float16 v8h __attribute__((ext_vector_type(8)));
typedef float v4f __attribute__((ext_vector_type(4)));
typedef float f2 __attribute__((ext_vector_type(2)));
typedef unsigned int u2v __attribute__((ext_vector_type(2)));

// ---------------------------------------------------------------------------
// FALLBACK fp32 GEMM — used only if ws is too small for the f16 buffers.
// ---------------------------------------------------------------------------
__global__ __launch_bounds__(256) void gemm_nt3(const float* __restrict__ A,
                                                const float* __restrict__ W0,
                                                const float* __restrict__ W1,
                                                const float* __restrict__ W2,
                                                float* __restrict__ Cbase,
                                                int M, int N, int Kd) {
  __shared__ float As[8][128];
  __shared__ float Bs[8][128];
  const int z = blockIdx.z;
  const float* W = (z == 0) ? W0 : (z == 1) ? W1 : W2;
  float* C = Cbase + (size_t)z * M * N;
  const int tid = threadIdx.x;
  const int bm = blockIdx.y * 128;
  const int bn = blockIdx.x * 128;
  const int lrow = tid >> 1;
  const int lcol = (tid & 1) * 4;
  const int rm = (tid >> 4) * 8;
  const int rn = (tid & 15) * 8;
  const float* Ap = A + (size_t)(bm + lrow) * Kd + lcol;
  const float* Wp = W + (size_t)(bn + lrow) * Kd + lcol;
  float acc[8][8];
#pragma unroll
  for (int i = 0; i < 8; i++)
#pragma unroll
    for (int j = 0; j < 8; j++) acc[i][j] = 0.f;
  float4 av = *(const float4*)Ap;
  float4 wv = *(const float4*)Wp;
  for (int d0 = 0; d0 < Kd; d0 += 8) {
    __syncthreads();
    As[lcol + 0][lrow] = av.x; As[lcol + 1][lrow] = av.y;
    As[lcol + 2][lrow] = av.z; As[lcol + 3][lrow] = av.w;
    Bs[lcol + 0][lrow] = wv.x; Bs[lcol + 1][lrow] = wv.y;
    Bs[lcol + 2][lrow] = wv.z; Bs[lcol + 3][lrow] = wv.w;
    __syncthreads();
    if (d0 + 8 < Kd) {
      av = *(const float4*)(Ap + d0 + 8);
      wv = *(const float4*)(Wp + d0 + 8);
    }
#pragma unroll
    for (int kk = 0; kk < 8; kk++) {
      const float4 a0 = *(const float4*)&As[kk][rm];
      const float4 a1 = *(const float4*)&As[kk][rm + 4];
      const float4 b0 = *(const float4*)&Bs[kk][rn];
      const float4 b1 = *(const float4*)&Bs[kk][rn + 4];
      const float ar[8] = {a0.x, a0.y, a0.z, a0.w, a1.x, a1.y, a1.z, a1.w};
      const float br[8] = {b0.x, b0.y, b0.z, b0.w, b1.x, b1.y, b1.z, b1.w};
#pragma unroll
      for (int i = 0; i < 8; i++)
#pragma unroll
        for (int j = 0; j < 8; j++) acc[i][j] = fmaf(ar[i], br[j], acc[i][j]);
    }
  }
#pragma unroll
  for (int i = 0; i < 8; i++) {
    float* cp = C + (size_t)(bm + rm + i) * N + bn + rn;
    float4 c0 = {acc[i][0], acc[i][1], acc[i][2], acc[i][3]};
    float4 c1 = {acc[i][4], acc[i][5], acc[i][6], acc[i][7]};
    *(float4*)cp = c0;
    *(float4*)(cp + 4) = c1;
  }
}

// ---------------------------------------------------------------------------
// Convert: x -> xh (single f16), Wq/Wk/Wv -> Wf (single f16).
// (hi/lo split dropped: absmax floor is W-quant dominated; x-side f16 error
// adds only in quadrature — ~7e-4 vs 4.9e-3 threshold.)
// ---------------------------------------------------------------------------
__global__ __launch_bounds__(256) void convert_f16(
    const float* __restrict__ x, const float* __restrict__ Wq,
    const float* __restrict__ Wk, const float* __restrict__ Wv,
    _Float16* __restrict__ xh, _Float16* __restrict__ Wf) {
  const size_t N4X = (size_t)BB * TT * DD / 4;
  const size_t N4W = (size_t)(HH * KK) * DD / 4;
  const size_t i = (size_t)blockIdx.x * 256 + threadIdx.x;
  if (i < N4X) {
    const float4 v = ((const float4*)x)[i];
    h4 hi;
    hi.x = (_Float16)v.x; hi.y = (_Float16)v.y;
    hi.z = (_Float16)v.z; hi.w = (_Float16)v.w;
    ((h4*)xh)[i] = hi;
  } else {
    const size_t j = i - N4X;
    const float* Ws = (j < N4W) ? Wq : (j < 2 * N4W) ? Wk : Wv;
    const size_t jj = (j < N4W) ? j : (j < 2 * N4W) ? (j - N4W) : (j - 2 * N4W);
    const float4 v = ((const float4*)Ws)[jj];
    h4 hi;
    hi.x = (_Float16)v.x; hi.y = (_Float16)v.y;
    hi.z = (_Float16)v.z; hi.w = (_Float16)v.w;
    ((h4*)Wf)[j] = hi;
  }
}

// ---------------------------------------------------------------------------
// MFMA GEMM: C[z] = xh*W[z]^T  (f16 in, fp32 out) — m97 structure, single A.
// ---------------------------------------------------------------------------
#define GLDS(gp, lp)                                              \
  __builtin_amdgcn_global_load_lds(                               \
      (const __attribute__((address_space(1))) void*)(gp),        \
      (__attribute__((address_space(3))) void*)(lp), 16, 0, 0)

__global__ __launch_bounds__(256) void gemm_mfma(
    const _Float16* __restrict__ xh, const _Float16* __restrict__ Wf,
    float* __restrict__ Cbase) {
  __shared__ float4 lraw[1024];  // 16 KB = Ah | Bs
  _Float16* Ah = (_Float16*)lraw;
  _Float16* Bs = Ah + 4096;

  const int z = blockIdx.z;
  const _Float16* W = Wf + (size_t)z * DD * (HH * KK);
  float* C = Cbase + (size_t)z * (BB * TT) * (HH * KK);

  const int tid = threadIdx.x;
  const int w = tid >> 6;
  const int lane = tid & 63;
  const int bm = blockIdx.y * 128;
  const int bn = blockIdx.x * 128;
  const int wm = (w & 1) * 64;
  const int wn = (w >> 1) * 64;
  const int m16 = lane & 15;
  const int quad = lane >> 4;

  const _Float16* gA = xh + (size_t)(bm + (tid >> 2)) * DD + (tid & 3) * 8;
  const _Float16* gB = W + (size_t)(bn + (tid >> 2)) * DD + (tid & 3) * 8;
  const int lb = w * 512;

  v4f acc[4][4];
#pragma unroll
  for (int i = 0; i < 4; i++)
#pragma unroll
    for (int j = 0; j < 4; j++) acc[i][j] = (v4f){0.f, 0.f, 0.f, 0.f};

  for (int d0 = 0; d0 < DD; d0 += 32) {
    GLDS(gA + d0, Ah + lb);
    GLDS(gA + d0 + 64 * DD, Ah + 2048 + lb);
    GLDS(gB + d0, Bs + lb);
    GLDS(gB + d0 + 64 * DD, Bs + 2048 + lb);
    __syncthreads();
    v8h ah[4], bw[4];
#pragma unroll
    for (int i = 0; i < 4; i++) {
      ah[i] = *(const v8h*)&Ah[(wm + i * 16 + m16) * 32 + quad * 8];
      bw[i] = *(const v8h*)&Bs[(wn + i * 16 + m16) * 32 + quad * 8];
    }
#pragma unroll
    for (int mi = 0; mi < 4; mi++)
#pragma unroll
      for (int ni = 0; ni < 4; ni++)
        acc[mi][ni] = __builtin_amdgcn_mfma_f32_16x16x32_f16(ah[mi], bw[ni],
                                                             acc[mi][ni], 0, 0, 0);
    __syncthreads();
  }
#pragma unroll
  for (int mi = 0; mi < 4; mi++) {
#pragma unroll
    for (int r = 0; r < 4; r++) {
      float* cp =
          C + (size_t)(bm + wm + mi * 16 + quad * 4 + r) * (HH * KK) + bn + wn + m16;
#pragma unroll
      for (int ni = 0; ni < 4; ni++) cp[ni * 16] = acc[mi][ni][r];
    }
  }
}

// ---------------------------------------------------------------------------
// alpha/beta projections (unchanged)
// ---------------------------------------------------------------------------
__global__ __launch_bounds__(64) void ab_proj(const float* __restrict__ x,
                                              const float* __restrict__ Wa,
                                              const float* __restrict__ ba,
                                              const float* __restrict__ Wb,
                                              const float* __restrict__ bb,
                                              float* __restrict__ abq) {
  const int row = blockIdx.x;
  const int g = blockIdx.y;
  const int h0 = (g & 1) * 8;
  const bool isA = (g < 2);
  const float* W = isA ? Wa : Wb;
  const int lane = threadIdx.x;
  const float* xr = x + (size_t)row * DD;
  float acc[8];
#pragma unroll
  for (int j = 0; j < 8; j++) acc[j] = 0.f;
  for (int d = lane; d < DD; d += 64) {
    const float xv = xr[d];
#pragma unroll
    for (int j = 0; j < 8; j++)
      acc[j] = fmaf(xv, W[(size_t)(h0 + j) * DD + d], acc[j]);
  }
#pragma unroll
  for (int j = 0; j < 8; j++) {
#pragma unroll
    for (int off = 32; off > 0; off >>= 1) acc[j] += __shfl_xor(acc[j], off, 64);
  }
  if (lane == 0) {
    if (isA) {
#pragma unroll
      for (int j = 0; j < 8; j++) {
        const float z = acc[j] + ba[h0 + j];
        abq[((size_t)row * HH + h0 + j) * 4 + 0] = 1.0f / (1.0f + expf(-z));
      }
    } else {
#pragma unroll
      for (int j = 0; j < 8; j++) {
        const float z = acc[j] + bb[h0 + j];
        const float sp = (z > 20.f) ? z : log1pf(expf(z));
        abq[((size_t)row * HH + h0 + j) * 4 + 1] = sp * 0.08838834764831845f;
      }
    }
  }
}

// ---------------------------------------------------------------------------
// l2-normalize q,k in place; kq = dot(qn,kn) -> abq slot 2 (unchanged)
// ---------------------------------------------------------------------------
__global__ __launch_bounds__(256) void norm_qk(float* __restrict__ q,
                                               float* __restrict__ k,
                                               float* __restrict__ abq) {
  const int vec = blockIdx.x * 4 + (threadIdx.x >> 6);
  const int l = threadIdx.x & 63;
  float* qp = q + (size_t)vec * 128;
  float* kp = k + (size_t)vec * 128;
  float q0 = qp[l], q1 = qp[l + 64];
  float k0 = kp[l], k1 = kp[l + 64];
  float sq = q0 * q0 + q1 * q1;
  float sk = k0 * k0 + k1 * k1;
#pragma unroll
  for (int off = 32; off > 0; off >>= 1) {
    sq += __shfl_xor(sq, off, 64);
    sk += __shfl_xor(sk, off, 64);
  }
  const float iq = 1.0f / fmaxf(sqrtf(sq), 1e-12f);
  const float ik = 1.0f / fmaxf(sqrtf(sk), 1e-12f);
  q0 *= iq; q1 *= iq; k0 *= ik; k1 *= ik;
  qp[l] = q0; qp[l + 64] = q1;
  kp[l] = k0; kp[l + 64] = k1;
  float pq = q0 * k0 + q1 * k1;
#pragma unroll
  for (int off = 32; off > 0; off >>= 1) pq += __shfl_xor(pq, off, 64);
  if (l == 0) abq[(size_t)vec * 4 + 2] = pq;
}

// ---------------------------------------------------------------------------
// Scan v8: v7 structure (32 lanes/row, 4 state floats, 2 waves/SIMD) with
// an instruction diet — v7 measured ~87 VALU/step/wave at 72.5% busy:
//  * packed fp32 (v_pk_fma_f32 via __builtin_elementwise_fma on float2)
//    for dot partials + state update
//  * uniform-base addressing: loads = uniformPtr[divergentConst + uniformOff]
//    so the backend uses saddr-form global_load with SALU offset bumps
//    (v7 baked divergence into pointers -> 64-bit VALU bumps every step)
//  * batched o-store: oo is identical in all 32 row-lanes after allreduce;
//    cndmask step j into lane ks==j, one masked store per 8 steps
// ---------------------------------------------------------------------------
#define DPP_ADD(x, ctrl)                                                     \
  ((x) + __int_as_float(__builtin_amdgcn_update_dpp(                         \
             0, __float_as_int(x), (ctrl), 0xF, 0xF, true)))

__device__ __forceinline__ float xadd32(float x) {
  // returns x[lane] + x[lane^32] in every lane (pure VALU)
  const u2v r = __builtin_amdgcn_permlane32_swap(__float_as_uint(x),
                                                 __float_as_uint(x), false,
                                                 false);
  return __uint_as_float(r.x) + __uint_as_float(r.y);
}

#define SCAN_STEP(kc, qc, vc, ac, jj)                                          \
  {                                                                            \
    const f2 ka = {kc.x, kc.y};                                                \
    const f2 kb2 = {kc.z, kc.w};                                               \
    const f2 qa = {qc.x, qc.y};                                                \
    const f2 qb2 = {qc.z, qc.w};                                               \
    const f2 pdk = __builtin_elementwise_fma(Sb, kb2, Sa * ka);                \
    const f2 pdq = __builtin_elementwise_fma(Sb, qb2, Sa * qa);                \
    float dk = pdk.x + pdk.y;                                                  \
    float dq = pdq.x + pdq.y;                                                  \
    dk = DPP_ADD(dk, 0xB1);  dq = DPP_ADD(dq, 0xB1);   /* width 2  */          \
    dk = DPP_ADD(dk, 0x4E);  dq = DPP_ADD(dq, 0x4E);   /* width 4  */          \
    dk = DPP_ADD(dk, 0x141); dq = DPP_ADD(dq, 0x141);  /* width 8  */          \
    dk = DPP_ADD(dk, 0x140); dq = DPP_ADD(dq, 0x140);  /* width 16 */          \
    dk = xadd32(dk);         dq = xadd32(dq);          /* width 32 */          \
    const float u = ac.y * fmaf(-ac.x, dk, vc);                                \
    const float oo = fmaf(ac.x, dq, u * ac.z);                                 \
    const f2 a2 = {ac.x, ac.x};                                                \
    const f2 u2 = {u, u};                                                      \
    Sa = __builtin_elementwise_fma(a2, Sa, u2 * ka);                           \
    Sb = __builtin_elementwise_fma(a2, Sb, u2 * kb2);                          \
    obuf = (ks == (jj)) ? oo : obuf;                                           \
  }

#define PD 8  // prefetch depth

__global__ __launch_bounds__(256, 2) void scan_kernel(
    const float* __restrict__ q, const float* __restrict__ k,
    const float* __restrict__ v, const float* __restrict__ abq,
    float* __restrict__ o) {
  const int bid = blockIdx.x;  // = s*32 + bh
  const int bh = bid & 31;
  const int s = bid >> 5;  // 0..15
  const int h = bh & 15;
  const int b = bh >> 4;
  const int tid = threadIdx.x;
  const int w = tid >> 6;
  const int lane = tid & 63;
  const int rg = (lane >> 4) & 1;                   // row within wave (0..1)
  const int ks = (lane & 15) | ((lane >> 5) << 4);  // k-slot 0..31 (4 floats)
  const int vrow = s * 8 + w * 2 + rg;

  const size_t base = (size_t)b * TT * 2048 + (size_t)h * KK;
  // uniform bases; divergent parts kept as small 32-bit indices
  const float* kU = k + base;
  const float* qU = q + base;
  const float* vU = v + base;
  const float* aU = abq + ((size_t)b * TT * HH + h) * 4;
  float* oU = o + base;
  const int vks = ks * 4;  // divergent, constant

  f2 Sa = {0.f, 0.f}, Sb = {0.f, 0.f};
  float obuf = 0.f;

  float4 kf[PD], qf[PD], af[PD];
  float vf[PD];
#pragma unroll
  for (int d = 0; d < PD; d++) {
    kf[d] = *(const float4*)(kU + vks + d * 2048);
    qf[d] = *(const float4*)(qU + vks + d * 2048);
    vf[d] = vU[vrow + d * 2048];
    af[d] = *(const float4*)(aU + d * 64);
  }

  int off = 0;   // uniform element offset, +2048 per step
  int aoff = 0;  // uniform abq offset, +64 per step
  for (int t0 = 0; t0 < TT - PD; t0 += PD) {
#pragma unroll
    for (int j = 0; j < PD; j++) {
      // consume slot j (no copy — loads below overwrite it afterwards)
      SCAN_STEP(kf[j], qf[j], vf[j], af[j], j);
      // reload slot j with step t0+j+PD
      kf[j] = *(const float4*)(kU + vks + off + (j + PD) * 2048);
      qf[j] = *(const float4*)(qU + vks + off + (j + PD) * 2048);
      vf[j] = vU[vrow + off + (j + PD) * 2048];
      af[j] = *(const float4*)(aU + aoff + (j + PD) * 64);
      __builtin_amdgcn_sched_barrier(0);  // loads may not sink past here
    }
    // lanes ks<8 hold steps t0+ks in obuf (oo is row-uniform)
    if (ks < 8) oU[vrow + off + ks * 2048] = obuf;
    off += PD * 2048;
    aoff += PD * 64;
  }
  // final PD steps: consume only
#pragma unroll
  for (int j = 0; j < PD; j++) {
    SCAN_STEP(kf[j], qf[j], vf[j], af[j], j);
  }
  if (ks < 8) oU[vrow + off + ks * 2048] = obuf;
}

// ---------------------------------------------------------------------------
extern "C" void kernel_launch(void* const* d_in, const int* in_sizes, int n_in,
                              void* d_out, int out_size, void* d_ws,
                              size_t ws_size, hipStream_t stream) {
  const float* x = (const float*)d_in[0];
  const float* Wq = (const float*)d_in[1];
  const float* Wk = (const float*)d_in[2];
  const float* Wv = (const float*)d_in[3];
  const float* Wa = (const float*)d_in[4];
  const float* ba = (const float*)d_in[5];
  const float* Wb = (const float*)d_in[6];
  const float* bb = (const float*)d_in[7];
  float* out = (float*)d_out;
  float* ws = (float*)d_ws;

  const size_t PROJ = (size_t)BB * TT * HH * KK;  // 8,388,608
  const size_t NABQ = (size_t)BB * TT * HH * 4;
  float* qw = ws;
  float* kw = ws + PROJ;
  float* vw = ws + 2 * PROJ;
  float* abq = ws + 3 * PROJ;
  _Float16* xh = (_Float16*)(abq + NABQ);
  _Float16* Wf = xh + (size_t)BB * TT * DD;
  const size_t NEED = (3 * PROJ + NABQ) * 4 +
                      ((size_t)BB * TT * DD + 3 * (size_t)(HH * KK) * DD) * 2;

  const int M = BB * TT;  // 4096
  const int N = HH * KK;  // 2048
  if (ws_size >= NEED) {
    const int cgrid = (int)(((size_t)BB * TT * DD / 4 + 3 * (size_t)N * DD / 4) / 256);
    convert_f16<<<cgrid, 256, 0, stream>>>(x, Wq, Wk, Wv, xh, Wf);
    gemm_mfma<<<dim3(N / 128, M / 128, 3), 256, 0, stream>>>(xh, Wf, qw);
  } else {
    gemm_nt3<<<dim3(N / 128, M / 128, 3), 256, 0, stream>>>(x, Wq, Wk, Wv, qw,
                                                            M, N, DD);
  }
  ab_proj<<<dim3(M, 4), 64, 0, stream>>>(x, Wa, ba, Wb, bb, abq);
  norm_qk<<<(BB * TT * HH) / 4, 256, 0, stream>>>(qw, kw, abq);
  scan_kernel<<<BB * HH * 16, 256, 0, stream>>>(qw, kw, vw, abq, out);
}

// Round 6
// 720.632 us; speedup vs baseline: 1.4752x; 1.0075x over previous
//
#include <hip/hip_runtime.h>
#include <math.h>

#define BB 2
#define TT 2048
#define DD 2048
#define HH 16
#define KK 128

typedef _Float16 h4 __attribute__((ext_vector_type(4)));
typedef _Float16 v8h __attribute__((ext_vector_type(8)));
typedef float v4f __attribute__((ext_vector_type(4)));
typedef float f2 __attribute__((ext_vector_type(2)));
typedef unsigned int u2v __attribute__((ext_vector_type(2)));

// ---------------------------------------------------------------------------
// FALLBACK fp32 GEMM — used only if ws is too small for the f16 buffers.
// ---------------------------------------------------------------------------
__global__ __launch_bounds__(256) void gemm_nt3(const float* __restrict__ A,
                                                const float* __restrict__ W0,
                                                const float* __restrict__ W1,
                                                const float* __restrict__ W2,
                                                float* __restrict__ Cbase,
                                                int M, int N, int Kd) {
  __shared__ float As[8][128];
  __shared__ float Bs[8][128];
  const int z = blockIdx.z;
  const float* W = (z == 0) ? W0 : (z == 1) ? W1 : W2;
  float* C = Cbase + (size_t)z * M * N;
  const int tid = threadIdx.x;
  const int bm = blockIdx.y * 128;
  const int bn = blockIdx.x * 128;
  const int lrow = tid >> 1;
  const int lcol = (tid & 1) * 4;
  const int rm = (tid >> 4) * 8;
  const int rn = (tid & 15) * 8;
  const float* Ap = A + (size_t)(bm + lrow) * Kd + lcol;
  const float* Wp = W + (size_t)(bn + lrow) * Kd + lcol;
  float acc[8][8];
#pragma unroll
  for (int i = 0; i < 8; i++)
#pragma unroll
    for (int j = 0; j < 8; j++) acc[i][j] = 0.f;
  float4 av = *(const float4*)Ap;
  float4 wv = *(const float4*)Wp;
  for (int d0 = 0; d0 < Kd; d0 += 8) {
    __syncthreads();
    As[lcol + 0][lrow] = av.x; As[lcol + 1][lrow] = av.y;
    As[lcol + 2][lrow] = av.z; As[lcol + 3][lrow] = av.w;
    Bs[lcol + 0][lrow] = wv.x; Bs[lcol + 1][lrow] = wv.y;
    Bs[lcol + 2][lrow] = wv.z; Bs[lcol + 3][lrow] = wv.w;
    __syncthreads();
    if (d0 + 8 < Kd) {
      av = *(const float4*)(Ap + d0 + 8);
      wv = *(const float4*)(Wp + d0 + 8);
    }
#pragma unroll
    for (int kk = 0; kk < 8; kk++) {
      const float4 a0 = *(const float4*)&As[kk][rm];
      const float4 a1 = *(const float4*)&As[kk][rm + 4];
      const float4 b0 = *(const float4*)&Bs[kk][rn];
      const float4 b1 = *(const float4*)&Bs[kk][rn + 4];
      const float ar[8] = {a0.x, a0.y, a0.z, a0.w, a1.x, a1.y, a1.z, a1.w};
      const float br[8] = {b0.x, b0.y, b0.z, b0.w, b1.x, b1.y, b1.z, b1.w};
#pragma unroll
      for (int i = 0; i < 8; i++)
#pragma unroll
        for (int j = 0; j < 8; j++) acc[i][j] = fmaf(ar[i], br[j], acc[i][j]);
    }
  }
#pragma unroll
  for (int i = 0; i < 8; i++) {
    float* cp = C + (size_t)(bm + rm + i) * N + bn + rn;
    float4 c0 = {acc[i][0], acc[i][1], acc[i][2], acc[i][3]};
    float4 c1 = {acc[i][4], acc[i][5], acc[i][6], acc[i][7]};
    *(float4*)cp = c0;
    *(float4*)(cp + 4) = c1;
  }
}

// ---------------------------------------------------------------------------
// Convert: x -> xh (single f16), Wq/Wk/Wv -> Wf (single f16).
// ---------------------------------------------------------------------------
__global__ __launch_bounds__(256) void convert_f16(
    const float* __restrict__ x, const float* __restrict__ Wq,
    const float* __restrict__ Wk, const float* __restrict__ Wv,
    _Float16* __restrict__ xh, _Float16* __restrict__ Wf) {
  const size_t N4X = (size_t)BB * TT * DD / 4;
  const size_t N4W = (size_t)(HH * KK) * DD / 4;
  const size_t i = (size_t)blockIdx.x * 256 + threadIdx.x;
  if (i < N4X) {
    const float4 v = ((const float4*)x)[i];
    h4 hi;
    hi.x = (_Float16)v.x; hi.y = (_Float16)v.y;
    hi.z = (_Float16)v.z; hi.w = (_Float16)v.w;
    ((h4*)xh)[i] = hi;
  } else {
    const size_t j = i - N4X;
    const float* Ws = (j < N4W) ? Wq : (j < 2 * N4W) ? Wk : Wv;
    const size_t jj = (j < N4W) ? j : (j < 2 * N4W) ? (j - N4W) : (j - 2 * N4W);
    const float4 v = ((const float4*)Ws)[jj];
    h4 hi;
    hi.x = (_Float16)v.x; hi.y = (_Float16)v.y;
    hi.z = (_Float16)v.z; hi.w = (_Float16)v.w;
    ((h4*)Wf)[j] = hi;
  }
}

// ---------------------------------------------------------------------------
// MFMA GEMM: C[z] = xh*W[z]^T  (f16 in, fp32 out) — m97 structure, single A.
// ---------------------------------------------------------------------------
#define GLDS(gp, lp)                                              \
  __builtin_amdgcn_global_load_lds(                               \
      (const __attribute__((address_space(1))) void*)(gp),        \
      (__attribute__((address_space(3))) void*)(lp), 16, 0, 0)

__global__ __launch_bounds__(256) void gemm_mfma(
    const _Float16* __restrict__ xh, const _Float16* __restrict__ Wf,
    float* __restrict__ Cbase) {
  __shared__ float4 lraw[1024];  // 16 KB = Ah | Bs
  _Float16* Ah = (_Float16*)lraw;
  _Float16* Bs = Ah + 4096;

  const int z = blockIdx.z;
  const _Float16* W = Wf + (size_t)z * DD * (HH * KK);
  float* C = Cbase + (size_t)z * (BB * TT) * (HH * KK);

  const int tid = threadIdx.x;
  const int w = tid >> 6;
  const int lane = tid & 63;
  const int bm = blockIdx.y * 128;
  const int bn = blockIdx.x * 128;
  const int wm = (w & 1) * 64;
  const int wn = (w >> 1) * 64;
  const int m16 = lane & 15;
  const int quad = lane >> 4;

  const _Float16* gA = xh + (size_t)(bm + (tid >> 2)) * DD + (tid & 3) * 8;
  const _Float16* gB = W + (size_t)(bn + (tid >> 2)) * DD + (tid & 3) * 8;
  const int lb = w * 512;

  v4f acc[4][4];
#pragma unroll
  for (int i = 0; i < 4; i++)
#pragma unroll
    for (int j = 0; j < 4; j++) acc[i][j] = (v4f){0.f, 0.f, 0.f, 0.f};

  for (int d0 = 0; d0 < DD; d0 += 32) {
    GLDS(gA + d0, Ah + lb);
    GLDS(gA + d0 + 64 * DD, Ah + 2048 + lb);
    GLDS(gB + d0, Bs + lb);
    GLDS(gB + d0 + 64 * DD, Bs + 2048 + lb);
    __syncthreads();
    v8h ah[4], bw[4];
#pragma unroll
    for (int i = 0; i < 4; i++) {
      ah[i] = *(const v8h*)&Ah[(wm + i * 16 + m16) * 32 + quad * 8];
      bw[i] = *(const v8h*)&Bs[(wn + i * 16 + m16) * 32 + quad * 8];
    }
#pragma unroll
    for (int mi = 0; mi < 4; mi++)
#pragma unroll
      for (int ni = 0; ni < 4; ni++)
        acc[mi][ni] = __builtin_amdgcn_mfma_f32_16x16x32_f16(ah[mi], bw[ni],
                                                             acc[mi][ni], 0, 0, 0);
    __syncthreads();
  }
#pragma unroll
  for (int mi = 0; mi < 4; mi++) {
#pragma unroll
    for (int r = 0; r < 4; r++) {
      float* cp =
          C + (size_t)(bm + wm + mi * 16 + quad * 4 + r) * (HH * KK) + bn + wn + m16;
#pragma unroll
      for (int ni = 0; ni < 4; ni++) cp[ni * 16] = acc[mi][ni][r];
    }
  }
}

// ---------------------------------------------------------------------------
// alpha/beta projections (unchanged)
// ---------------------------------------------------------------------------
__global__ __launch_bounds__(64) void ab_proj(const float* __restrict__ x,
                                              const float* __restrict__ Wa,
                                              const float* __restrict__ ba,
                                              const float* __restrict__ Wb,
                                              const float* __restrict__ bb,
                                              float* __restrict__ abq) {
  const int row = blockIdx.x;
  const int g = blockIdx.y;
  const int h0 = (g & 1) * 8;
  const bool isA = (g < 2);
  const float* W = isA ? Wa : Wb;
  const int lane = threadIdx.x;
  const float* xr = x + (size_t)row * DD;
  float acc[8];
#pragma unroll
  for (int j = 0; j < 8; j++) acc[j] = 0.f;
  for (int d = lane; d < DD; d += 64) {
    const float xv = xr[d];
#pragma unroll
    for (int j = 0; j < 8; j++)
      acc[j] = fmaf(xv, W[(size_t)(h0 + j) * DD + d], acc[j]);
  }
#pragma unroll
  for (int j = 0; j < 8; j++) {
#pragma unroll
    for (int off = 32; off > 0; off >>= 1) acc[j] += __shfl_xor(acc[j], off, 64);
  }
  if (lane == 0) {
    if (isA) {
#pragma unroll
      for (int j = 0; j < 8; j++) {
        const float z = acc[j] + ba[h0 + j];
        abq[((size_t)row * HH + h0 + j) * 4 + 0] = 1.0f / (1.0f + expf(-z));
      }
    } else {
#pragma unroll
      for (int j = 0; j < 8; j++) {
        const float z = acc[j] + bb[h0 + j];
        const float sp = (z > 20.f) ? z : log1pf(expf(z));
        abq[((size_t)row * HH + h0 + j) * 4 + 1] = sp * 0.08838834764831845f;
      }
    }
  }
}

// ---------------------------------------------------------------------------
// l2-normalize q,k in place; kq = dot(qn,kn) -> abq slot 2 (unchanged)
// ---------------------------------------------------------------------------
__global__ __launch_bounds__(256) void norm_qk(float* __restrict__ q,
                                               float* __restrict__ k,
                                               float* __restrict__ abq) {
  const int vec = blockIdx.x * 4 + (threadIdx.x >> 6);
  const int l = threadIdx.x & 63;
  float* qp = q + (size_t)vec * 128;
  float* kp = k + (size_t)vec * 128;
  float q0 = qp[l], q1 = qp[l + 64];
  float k0 = kp[l], k1 = kp[l + 64];
  float sq = q0 * q0 + q1 * q1;
  float sk = k0 * k0 + k1 * k1;
#pragma unroll
  for (int off = 32; off > 0; off >>= 1) {
    sq += __shfl_xor(sq, off, 64);
    sk += __shfl_xor(sk, off, 64);
  }
  const float iq = 1.0f / fmaxf(sqrtf(sq), 1e-12f);
  const float ik = 1.0f / fmaxf(sqrtf(sk), 1e-12f);
  q0 *= iq; q1 *= iq; k0 *= ik; k1 *= ik;
  qp[l] = q0; qp[l + 64] = q1;
  kp[l] = k0; kp[l + 64] = k1;
  float pq = q0 * k0 + q1 * k1;
#pragma unroll
  for (int off = 32; off > 0; off >>= 1) pq += __shfl_xor(pq, off, 64);
  if (l == 0) abq[(size_t)vec * 4 + 2] = pq;
}

// ---------------------------------------------------------------------------
// Scan v9: LDS-staged k/q/ab with global_load_lds, double-buffered in
// 8-step groups, counted vmcnt(11) (never 0 mid-loop), raw s_barrier
// (inline asm, no implicit vmcnt(0) drain). Math identical to v8.
// v8 diagnosis: VGPR=56 proves regalloc collapsed the depth-8 register
// prefetch -> latency leak (31% idle), plus 8x intra-block duplicate
// k/q VMEM. LDS staging fixes both: per step = 3 ds_read_b128 + ~27 VALU;
// VMEM ~1.4/step amortized; latency hidden a full group ahead.
// ---------------------------------------------------------------------------
#define DPP_ADD(x, ctrl)                                                     \
  ((x) + __int_as_float(__builtin_amdgcn_update_dpp(                         \
             0, __float_as_int(x), (ctrl), 0xF, 0xF, true)))

__device__ __forceinline__ float xadd32(float x) {
  // returns x[lane] + x[lane^32] in every lane (pure VALU)
  const u2v r = __builtin_amdgcn_permlane32_swap(__float_as_uint(x),
                                                 __float_as_uint(x), false,
                                                 false);
  return __uint_as_float(r.x) + __uint_as_float(r.y);
}

#define SBAR() asm volatile("s_barrier" ::: "memory")
#define WAITV(n) asm volatile("s_waitcnt vmcnt(" #n ")" ::: "memory")

// one recurrence step; sources already in registers
#define SCAN_MATH(kc, qc, vc, ac, jj, obname)                                  \
  {                                                                            \
    const f2 ka = {kc.x, kc.y};                                                \
    const f2 kb2 = {kc.z, kc.w};                                               \
    const f2 qa = {qc.x, qc.y};                                                \
    const f2 qb2 = {qc.z, qc.w};                                               \
    const f2 pdk = __builtin_elementwise_fma(Sb, kb2, Sa * ka);                \
    const f2 pdq = __builtin_elementwise_fma(Sb, qb2, Sa * qa);                \
    float dk = pdk.x + pdk.y;                                                  \
    float dq = pdq.x + pdq.y;                                                  \
    dk = DPP_ADD(dk, 0xB1);  dq = DPP_ADD(dq, 0xB1);   /* width 2  */          \
    dk = DPP_ADD(dk, 0x4E);  dq = DPP_ADD(dq, 0x4E);   /* width 4  */          \
    dk = DPP_ADD(dk, 0x141); dq = DPP_ADD(dq, 0x141);  /* width 8  */          \
    dk = DPP_ADD(dk, 0x140); dq = DPP_ADD(dq, 0x140);  /* width 16 */          \
    dk = xadd32(dk);         dq = xadd32(dq);          /* width 32 */          \
    const float u = ac.y * fmaf(-ac.x, dk, vc);                                \
    const float oo = fmaf(ac.x, dq, u * ac.z);                                 \
    const f2 a2 = {ac.x, ac.x};                                                \
    const f2 u2 = {u, u};                                                      \
    Sa = __builtin_elementwise_fma(a2, Sa, u2 * ka);                           \
    Sb = __builtin_elementwise_fma(a2, Sb, u2 * kb2);                          \
    obname = (ks == (jj)) ? oo : obname;                                       \
  }

// stage 8-step group starting at row tg into buffer bi (3 GLDS + 8 v-loads)
#define STAGE(bi, tg)                                                          \
  {                                                                            \
    const float* gk =                                                          \
        kU + (size_t)((tg) + 2 * w + (lane >> 5)) * 2048 + (lane & 31) * 4;    \
    GLDS(gk, &Kb[bi][2 * w][0]);                                               \
    const float* gq =                                                          \
        qU + (size_t)((tg) + 2 * w + (lane >> 5)) * 2048 + (lane & 31) * 4;    \
    GLDS(gq, &Qb[bi][2 * w][0]);                                               \
    if (lane < 8) GLDS(aU + (size_t)((tg) + lane) * 64, &Ab[bi][0][0]);        \
    _Pragma("unroll") for (int jj = 0; jj < 8; jj++)                           \
        vf##bi[jj] = vU[vrow + (size_t)((tg) + jj) * 2048];                    \
  }

#define COMPUTE_GROUP(bi, obname)                                              \
  float obname = 0.f;                                                          \
  _Pragma("unroll") for (int j = 0; j < 8; j++) {                              \
    const float4 kc = *(const float4*)&Kb[bi][j][ks4];                         \
    const float4 qc = *(const float4*)&Qb[bi][j][ks4];                         \
    const float4 ac = *(const float4*)&Ab[bi][j][0];                           \
    const float vc = vf##bi[j];                                                \
    SCAN_MATH(kc, qc, vc, ac, j, obname);                                      \
  }

__global__ __launch_bounds__(256, 2) void scan_kernel(
    const float* __restrict__ q, const float* __restrict__ k,
    const float* __restrict__ v, const float* __restrict__ abq,
    float* __restrict__ o) {
  __shared__ float Kb[2][8][128];  // 4 KB per buffer
  __shared__ float Qb[2][8][128];  // 4 KB per buffer
  __shared__ float Ab[2][8][4];    // 128 B per buffer

  const int bid = blockIdx.x;  // = s*32 + bh
  const int bh = bid & 31;
  const int s = bid >> 5;  // 0..15
  const int h = bh & 15;
  const int b = bh >> 4;
  const int tid = threadIdx.x;
  const int w = tid >> 6;
  const int lane = tid & 63;
  const int rg = (lane >> 4) & 1;                   // row within wave (0..1)
  const int ks = (lane & 15) | ((lane >> 5) << 4);  // k-slot 0..31 (4 floats)
  const int ks4 = ks * 4;
  const int vrow = s * 8 + w * 2 + rg;

  const size_t base = (size_t)b * TT * 2048 + (size_t)h * KK;
  const float* kU = k + base;
  const float* qU = q + base;
  const float* vU = v + base;
  const float* aU = abq + ((size_t)b * TT * HH + h) * 4;
  float* oU = o + base;

  f2 Sa = {0.f, 0.f}, Sb = {0.f, 0.f};
  float vf0[8], vf1[8];

  // prologue: stage groups 0 and 1
  STAGE(0, 0);
  STAGE(1, 8);
  WAITV(11);  // group 0's 11 loads complete (group 1's 11 still in flight)
  SBAR();
  __builtin_amdgcn_sched_barrier(0);

  int tg = 0;  // first row of current even group
  for (int gp = 0; gp < TT / 8; gp += 2) {
    // ---- even group (buffer 0)
    COMPUTE_GROUP(0, ob0);
    if (ks < 8) oU[vrow + (size_t)(tg + ks) * 2048] = ob0;
    SBAR();  // all waves done reading buf0 -> safe to overwrite
    if (gp + 2 < TT / 8) {
      STAGE(0, tg + 16);
      WAITV(11);  // odd group's loads (issued last round) complete
    } else {
      WAITV(0);
    }
    SBAR();  // buf1 ready for everyone
    __builtin_amdgcn_sched_barrier(0);

    // ---- odd group (buffer 1)
    COMPUTE_GROUP(1, ob1);
    if (ks < 8) oU[vrow + (size_t)(tg + 8 + ks) * 2048] = ob1;
    SBAR();
    if (gp + 3 < TT / 8) {
      STAGE(1, tg + 24);
      WAITV(11);
    } else {
      WAITV(0);
    }
    SBAR();
    __builtin_amdgcn_sched_barrier(0);

    tg += 16;
  }
}

// ---------------------------------------------------------------------------
extern "C" void kernel_launch(void* const* d_in, const int* in_sizes, int n_in,
                              void* d_out, int out_size, void* d_ws,
                              size_t ws_size, hipStream_t stream) {
  const float* x = (const float*)d_in[0];
  const float* Wq = (const float*)d_in[1];
  const float* Wk = (const float*)d_in[2];
  const float* Wv = (const float*)d_in[3];
  const float* Wa = (const float*)d_in[4];
  const float* ba = (const float*)d_in[5];
  const float* Wb = (const float*)d_in[6];
  const float* bb = (const float*)d_in[7];
  float* out = (float*)d_out;
  float* ws = (float*)d_ws;

  const size_t PROJ = (size_t)BB * TT * HH * KK;  // 8,388,608
  const size_t NABQ = (size_t)BB * TT * HH * 4;
  float* qw = ws;
  float* kw = ws + PROJ;
  float* vw = ws + 2 * PROJ;
  float* abq = ws + 3 * PROJ;
  _Float16* xh = (_Float16*)(abq + NABQ);
  _Float16* Wf = xh + (size_t)BB * TT * DD;
  const size_t NEED = (3 * PROJ + NABQ) * 4 +
                      ((size_t)BB * TT * DD + 3 * (size_t)(HH * KK) * DD) * 2;

  const int M = BB * TT;  // 4096
  const int N = HH * KK;  // 2048
  if (ws_size >= NEED) {
    const int cgrid = (int)(((size_t)BB * TT * DD / 4 + 3 * (size_t)N * DD / 4) / 256);
    convert_f16<<<cgrid, 256, 0, stream>>>(x, Wq, Wk, Wv, xh, Wf);
    gemm_mfma<<<dim3(N / 128, M / 128, 3), 256, 0, stream>>>(xh, Wf, qw);
  } else {
    gemm_nt3<<<dim3(N / 128, M / 128, 3), 256, 0, stream>>>(x, Wq, Wk, Wv, qw,
                                                            M, N, DD);
  }
  ab_proj<<<dim3(M, 4), 64, 0, stream>>>(x, Wa, ba, Wb, bb, abq);
  norm_qk<<<(BB * TT * HH) / 4, 256, 0, stream>>>(qw, kw, abq);
  scan_kernel<<<BB * HH * 16, 256, 0, stream>>>(qw, kw, vw, abq, out);
}